// Round 29
// baseline (34567.194 us; speedup 1.0000x reference)
//
#include <hip/hip_runtime.h>

// SNN forward — bitwise numpy/OpenBLAS(kc=512) f32 semantics (verified R21-28,
// absmax=0.0039): per C element an ascending-k f32 FMA chain with a panel
// break at k=512 (csum = p1 + p2), elementwise f32 in reference order.
// R29 = R25 (best, 28.8ms) with BK 32->64: halves barrier count again
// (R22->R24 showed BK16->32 = +10%). Single-buffered, NO prefetch arrays
// (R23/R26 lesson), VGPR ~120, LDS 48KB (3 blocks/CU >= measured residency).

#pragma clang fp contract(off)

#define HDIM 1024
#define SPB (HDIM / 8)  // spike bytes per row = 128
#define BATCH 16384
#define NSTEP 25
#define BMR 128  // tile rows
#define BNC 64   // tile cols
#define BK 64
#define NKT (HDIM / BK)  // 16 tiles; panel fold after kt=7 (k=512) and kt=15
#define KC 512

// ---- staging: A f32 tile [64][128] (gemm_cur only) ----
__device__ __forceinline__ void stage_a_f32(const float* __restrict__ g, float* s,
                                            int tid, int kt) {
  int row = tid & 127, c = tid >> 7;  // c in 0..1
  const float* src = g + (size_t)row * HDIM + kt * BK + c * 32;
  int k0 = c * 32;
#pragma unroll
  for (int q4 = 0; q4 < 8; ++q4) {
    float4 v = *(const float4*)(src + q4 * 4);
    s[(k0 + q4 * 4 + 0) * BMR + row] = v.x;
    s[(k0 + q4 * 4 + 1) * BMR + row] = v.y;
    s[(k0 + q4 * 4 + 2) * BMR + row] = v.z;
    s[(k0 + q4 * 4 + 3) * BMR + row] = v.w;
  }
}

// ---- staging: A bitpacked-spike tile [64][128] (bits -> exact 0.0f/1.0f) ----
__device__ __forceinline__ void stage_a_u1(const unsigned char* __restrict__ g, float* s,
                                           int tid, int kt) {
  int row = tid & 127, c = tid >> 7;  // c in 0..1
  unsigned int v = *(const unsigned int*)(g + (size_t)row * SPB + kt * 8 + c * 4);
  int k0 = c * 32;
#pragma unroll
  for (int q = 0; q < 32; ++q)
    s[(k0 + q) * BMR + row] = (float)((v >> q) & 1u);
}

// ---- staging: B (weights) tile [64][64] ----
__device__ __forceinline__ void stage_b(const float* __restrict__ g, float* s,
                                        int tid, int kt) {
  int row = tid & 63, c = tid >> 6;  // c in 0..3
  const float* src = g + (size_t)row * HDIM + kt * BK + c * 16;
  int k0 = c * 16;
#pragma unroll
  for (int q4 = 0; q4 < 4; ++q4) {
    float4 v = *(const float4*)(src + q4 * 4);
    s[(k0 + q4 * 4 + 0) * BNC + row] = v.x;
    s[(k0 + q4 * 4 + 1) * BNC + row] = v.y;
    s[(k0 + q4 * 4 + 2) * BNC + row] = v.z;
    s[(k0 + q4 * 4 + 3) * BNC + row] = v.w;
  }
}

// one K-pass: kc=512-panel ascending FMA chain for a 4x8 micro-tile.
// m0 = (tid>>3)*4, n0 = (tid&7)*8. Single-buffered, 2 barriers per BK=64 tile.
template <bool AU1>
__device__ __forceinline__ void kpass(const void* __restrict__ Ag,
                                      const float* __restrict__ Bg,
                                      float* sA, float* sB, int tid, int m0, int n0,
                                      float csum[4][8]) {
  float p[4][8];
#pragma unroll
  for (int m = 0; m < 4; ++m)
#pragma unroll
    for (int n = 0; n < 8; ++n) { csum[m][n] = 0.0f; p[m][n] = 0.0f; }

#pragma unroll 1
  for (int kt = 0; kt < NKT; ++kt) {
    if (AU1) stage_a_u1((const unsigned char*)Ag, sA, tid, kt);
    else     stage_a_f32((const float*)Ag, sA, tid, kt);
    stage_b(Bg, sB, tid, kt);
    __syncthreads();
#pragma unroll
    for (int k = 0; k < BK; ++k) {
      float a[4], b[8];
      *(float4*)&a[0] = *(const float4*)&sA[k * BMR + m0];
      *(float4*)&b[0] = *(const float4*)&sB[k * BNC + n0];
      *(float4*)&b[4] = *(const float4*)&sB[k * BNC + n0 + 4];
#pragma unroll
      for (int m = 0; m < 4; ++m)
#pragma unroll
        for (int n = 0; n < 8; ++n)
          p[m][n] = __builtin_fmaf(a[m], b[n], p[m][n]);
    }
    if (((kt + 1) * BK) % KC == 0) {  // panel boundary: C += panel (kt=7,15)
#pragma unroll
      for (int m = 0; m < 4; ++m)
#pragma unroll
        for (int n = 0; n < 8; ++n) { csum[m][n] = csum[m][n] + p[m][n]; p[m][n] = 0.0f; }
    }
    __syncthreads();
  }
}

// cur1 = x@W1.T + b1
__global__ __launch_bounds__(256) void gemm_cur(const float* __restrict__ A,
                                                const float* __restrict__ B,
                                                const float* __restrict__ bias,
                                                float* __restrict__ outv) {
  __shared__ float sA[BK * BMR];
  __shared__ float sB[BK * BNC];
  const int tid = threadIdx.x;
  const int m0 = (tid >> 3) * 4, n0 = (tid & 7) * 8;
  const int bm = blockIdx.y, bn = blockIdx.x;
  float csum[4][8];
  kpass<false>(A + (size_t)bm * BMR * HDIM, B + (size_t)bn * BNC * HDIM,
               sA, sB, tid, m0, n0, csum);
  const int colb = bn * BNC + n0;
  float4 bia0 = *(const float4*)&bias[colb];
  float4 bia1 = *(const float4*)&bias[colb + 4];
  const float bi[8] = {bia0.x, bia0.y, bia0.z, bia0.w, bia1.x, bia1.y, bia1.z, bia1.w};
#pragma unroll
  for (int m = 0; m < 4; ++m) {
    size_t idx = (size_t)(bm * BMR + m0 + m) * HDIM + colb;
    float o[8];
#pragma unroll
    for (int n = 0; n < 8; ++n) o[n] = csum[m][n] + bi[n];
    *(float4*)&outv[idx] = *(float4*)&o[0];
    *(float4*)&outv[idx + 4] = *(float4*)&o[4];
  }
}

// t=0 layer1 (spikes exactly +0): mem1 = ((((0.5*0+cur1)+0)+V1b)-0); spike bits out.
__global__ __launch_bounds__(256) void l1_t0(const float* __restrict__ cur1,
                                             const float* __restrict__ vb,
                                             float* __restrict__ memv,
                                             unsigned char* __restrict__ spk_out) {
  size_t i = ((size_t)blockIdx.x * 256 + threadIdx.x) * 8;
  int col = (int)(i & (HDIM - 1));
  size_t row = i >> 10;
  float au[8], tn[8];
  *(float4*)&au[0] = *(const float4*)&cur1[i];
  *(float4*)&au[4] = *(const float4*)&cur1[i + 4];
  float4 v0 = *(const float4*)&vb[col];
  float4 v1 = *(const float4*)&vb[col + 4];
  const float vbv[8] = {v0.x, v0.y, v0.z, v0.w, v1.x, v1.y, v1.z, v1.w};
  unsigned int bits = 0;
#pragma unroll
  for (int n = 0; n < 8; ++n) {
    float t = 0.5f * 0.0f;
    t = t + au[n];
    t = t + 0.0f;
    t = t + vbv[n];
    t = t - 0.0f;
    tn[n] = t;
    bits |= (((t - 1.0f) > 0.0f) ? 1u : 0u) << n;
  }
  *(float4*)&memv[i] = *(float4*)&tn[0];
  *(float4*)&memv[i + 4] = *(float4*)&tn[4];
  spk_out[row * SPB + (col >> 3)] = (unsigned char)bits;
}

// layer1: rec1 = spk1p@V1w.T ; mem1 = 0.5*mem1 + cur1 + rec1 + V1b - reset
__global__ __launch_bounds__(256) void gemm_l1(
    const unsigned char* __restrict__ A, const float* __restrict__ B,
    const float* __restrict__ vb, const float* __restrict__ cur1,
    float* __restrict__ memv, unsigned char* __restrict__ spk_out) {
  __shared__ float sA[BK * BMR];
  __shared__ float sB[BK * BNC];
  const int tid = threadIdx.x;
  const int m0 = (tid >> 3) * 4, n0 = (tid & 7) * 8;
  const int bm = blockIdx.y, bn = blockIdx.x;
  float csum[4][8];
  kpass<true>(A + (size_t)bm * BMR * SPB, B + (size_t)bn * BNC * HDIM,
              sA, sB, tid, m0, n0, csum);
  const int colb = bn * BNC + n0;
  float4 v0 = *(const float4*)&vb[colb];
  float4 v1 = *(const float4*)&vb[colb + 4];
  const float vbv[8] = {v0.x, v0.y, v0.z, v0.w, v1.x, v1.y, v1.z, v1.w};
#pragma unroll
  for (int m = 0; m < 4; ++m) {
    size_t row = (size_t)(bm * BMR + m0 + m);
    size_t idx = row * HDIM + colb;
    float mo[8], au[8], tn[8];
    *(float4*)&mo[0] = *(const float4*)&memv[idx];
    *(float4*)&mo[4] = *(const float4*)&memv[idx + 4];
    *(float4*)&au[0] = *(const float4*)&cur1[idx];
    *(float4*)&au[4] = *(const float4*)&cur1[idx + 4];
    unsigned int bits = 0;
#pragma unroll
    for (int n = 0; n < 8; ++n) {
      float reset = (mo[n] > 1.0f) ? 1.0f : 0.0f;
      float t = 0.5f * mo[n];
      t = t + au[n];
      t = t + csum[m][n];
      t = t + vbv[n];
      t = t - reset;
      tn[n] = t;
      bits |= (((t - 1.0f) > 0.0f) ? 1u : 0u) << n;
    }
    *(float4*)&memv[idx] = *(float4*)&tn[0];
    *(float4*)&memv[idx + 4] = *(float4*)&tn[4];
    spk_out[row * SPB + (colb >> 3)] = (unsigned char)bits;
  }
}

// layer2 fused: cur2 = spk1n@W2.T + b2 ; rec2 = spk2p@V2w.T (skip2 -> exact +0);
// mem2 = 0.5*mem2 + cur2 + rec2 + V2b - reset ; spike bits/ssum out.
__global__ __launch_bounds__(256) void gemm_l2f(
    const unsigned char* __restrict__ A1, const float* __restrict__ B1,
    const unsigned char* __restrict__ A2, const float* __restrict__ B2,
    const float* __restrict__ bias, const float* __restrict__ vb,
    float* __restrict__ memv, unsigned char* __restrict__ spk_out,
    unsigned char* __restrict__ ssum, int skip2) {
  __shared__ float sA[BK * BMR];
  __shared__ float sB[BK * BNC];
  const int tid = threadIdx.x;
  const int m0 = (tid >> 3) * 4, n0 = (tid & 7) * 8;
  const int bm = blockIdx.y, bn = blockIdx.x;
  float dot1[4][8], csum[4][8];
  kpass<true>(A1 + (size_t)bm * BMR * SPB, B1 + (size_t)bn * BNC * HDIM,
              sA, sB, tid, m0, n0, dot1);
  if (skip2) {
#pragma unroll
    for (int m = 0; m < 4; ++m)
#pragma unroll
      for (int n = 0; n < 8; ++n) csum[m][n] = 0.0f;  // zero-spike chain == +0
  } else {
    __syncthreads();
    kpass<true>(A2 + (size_t)bm * BMR * SPB, B2 + (size_t)bn * BNC * HDIM,
                sA, sB, tid, m0, n0, csum);
  }
  const int colb = bn * BNC + n0;
  float4 b0 = *(const float4*)&bias[colb];
  float4 b1v = *(const float4*)&bias[colb + 4];
  const float bi[8] = {b0.x, b0.y, b0.z, b0.w, b1v.x, b1v.y, b1v.z, b1v.w};
  float4 v0 = *(const float4*)&vb[colb];
  float4 v1 = *(const float4*)&vb[colb + 4];
  const float vbv[8] = {v0.x, v0.y, v0.z, v0.w, v1.x, v1.y, v1.z, v1.w};
#pragma unroll
  for (int m = 0; m < 4; ++m) {
    size_t row = (size_t)(bm * BMR + m0 + m);
    size_t idx = row * HDIM + colb;
    float mo[8], tn[8];
    *(float4*)&mo[0] = *(const float4*)&memv[idx];
    *(float4*)&mo[4] = *(const float4*)&memv[idx + 4];
    unsigned int bits = 0;
#pragma unroll
    for (int n = 0; n < 8; ++n) {
      float reset = (mo[n] > 1.0f) ? 1.0f : 0.0f;
      float cur2 = dot1[m][n] + bi[n];
      float t = 0.5f * mo[n];
      t = t + cur2;
      t = t + csum[m][n];
      t = t + vbv[n];
      t = t - reset;
      tn[n] = t;
      bits |= (((t - 1.0f) > 0.0f) ? 1u : 0u) << n;
    }
    *(float4*)&memv[idx] = *(float4*)&tn[0];
    *(float4*)&memv[idx + 4] = *(float4*)&tn[4];
    spk_out[row * SPB + (colb >> 3)] = (unsigned char)bits;
    unsigned long long old = *(unsigned long long*)&ssum[idx];
    unsigned long long ns = 0;
#pragma unroll
    for (int n = 0; n < 8; ++n) {
      unsigned char c = (unsigned char)(((old >> (8 * n)) & 0xFF) + ((bits >> n) & 1u));
      ns |= ((unsigned long long)c) << (8 * n);
    }
    *(unsigned long long*)&ssum[idx] = ns;
  }
}

// out[b,o] = ((ssum[b,:]/25) . W3[o,:]) + b3[o], kc=512 panel rounding.
__global__ __launch_bounds__(256) void out_blas(const unsigned char* __restrict__ ssum,
                                                const float* __restrict__ W3,
                                                const float* __restrict__ b3,
                                                float* __restrict__ out) {
  int t = blockIdx.x * 256 + threadIdx.x;
  int b = t >> 4, o = t & 15;
  if (o >= 10) return;
  const unsigned char* sp = ssum + (size_t)b * HDIM;
  const float* wp = W3 + (size_t)o * HDIM;
  float csum = 0.0f, p = 0.0f;
#pragma unroll 4
  for (int k = 0; k < HDIM; ++k) {
    float sv = (float)sp[k] / 25.0f;
    p = __builtin_fmaf(sv, wp[k], p);
    if ((k + 1) % KC == 0) { csum = csum + p; p = 0.0f; }
  }
  out[(size_t)b * 10 + o] = csum + b3[o];
}

extern "C" void kernel_launch(void* const* d_in, const int* in_sizes, int n_in,
                              void* d_out, int out_size, void* d_ws, size_t ws_size,
                              hipStream_t stream) {
  const float* x = (const float*)d_in[0];
  const float* W1 = (const float*)d_in[1];
  const float* b1 = (const float*)d_in[2];
  const float* V1w = (const float*)d_in[3];
  const float* V1b = (const float*)d_in[4];
  const float* W2 = (const float*)d_in[5];
  const float* b2 = (const float*)d_in[6];
  const float* V2w = (const float*)d_in[7];
  const float* V2b = (const float*)d_in[8];
  const float* W3 = (const float*)d_in[9];
  const float* b3 = (const float*)d_in[10];
  float* out = (float*)d_out;

  char* ws = (char*)d_ws;
  // per-row: cur1, mem1, mem2 (f32) + 4 bitpacked spike bufs + ssum (u8)
  const size_t per_row = (size_t)HDIM * 4 * 3 + 4 * SPB + (size_t)HDIM;
  size_t rows = BATCH;
  while (rows > 128 && rows * per_row > ws_size) rows >>= 1;
  const int nchunk = (int)(BATCH / rows);
  const size_t RH = rows * (size_t)HDIM;
  const size_t RS = rows * (size_t)SPB;

  size_t off = 0;
  float* cur1 = (float*)(ws + off); off += RH * 4;
  float* mem1 = (float*)(ws + off); off += RH * 4;
  float* mem2 = (float*)(ws + off); off += RH * 4;
  unsigned char *spk1[2], *spk2[2];
  spk1[0] = (unsigned char*)(ws + off); off += RS;
  spk1[1] = (unsigned char*)(ws + off); off += RS;
  spk2[0] = (unsigned char*)(ws + off); off += RS;
  spk2[1] = (unsigned char*)(ws + off); off += RS;
  unsigned char* ssum = (unsigned char*)(ws + off); off += RH;

  dim3 grid(HDIM / BNC, (unsigned)(rows / BMR));  // (16, rows/128)

  for (int c = 0; c < nchunk; ++c) {
    const float* xc = x + (size_t)c * RH;
    float* outc = out + (size_t)c * rows * 10;

    hipMemsetAsync(mem2, 0, RH * 4, stream);
    hipMemsetAsync(ssum, 0, RH, stream);

    // cur1 = x@W1.T + b1 (loop-invariant)
    gemm_cur<<<grid, 256, 0, stream>>>(xc, W1, b1, cur1);

    for (int t = 0; t < NSTEP; ++t) {
      int rd = t & 1, wr = rd ^ 1;
      if (t == 0) {
        l1_t0<<<(unsigned)(RH / (256 * 8)), 256, 0, stream>>>(cur1, V1b, mem1, spk1[wr]);
      } else {
        gemm_l1<<<grid, 256, 0, stream>>>(spk1[rd], V1w, V1b, cur1, mem1, spk1[wr]);
      }
      gemm_l2f<<<grid, 256, 0, stream>>>(spk1[wr], W2, spk2[rd], V2w, b2, V2b,
                                         mem2, spk2[wr], ssum, t == 0 ? 1 : 0);
    }
    out_blas<<<(unsigned)(rows * 16 / 256), 256, 0, stream>>>(ssum, W3, b3, outc);
  }
}

// Round 30
// 28793.143 us; speedup vs baseline: 1.2005x; 1.2005x over previous
//
#include <hip/hip_runtime.h>

// SNN forward — bitwise numpy/OpenBLAS(kc=512) f32 semantics (verified R21-29,
// absmax=0.0039): per C element an ascending-k f32 FMA chain with a panel
// break at k=512 (csum = p1 + p2), elementwise f32 in reference order.
// R30 = R25 verbatim (best verified: 28.8ms). Parameter space mapped:
// BK16/64, double-buffer, prefetch, A-in-registers all regress via the
// VGPR-128 / LDS-occupancy cliffs. kc-panel fold pins micro-tile at 4x8
// (csum+p = 64 VGPR); at that shape LDS+VALU jointly saturate ~60%.
// 91 TF = 58% of f32 vector peak (MFMA forbidden by bitwise semantics).

#pragma clang fp contract(off)

#define HDIM 1024
#define SPB (HDIM / 8)  // spike bytes per row = 128
#define BATCH 16384
#define NSTEP 25
#define BMR 128  // tile rows
#define BNC 64   // tile cols
#define BK 32
#define NKT (HDIM / BK)  // 32 tiles; panel fold after kt=15 (k=512) and kt=31
#define KC 512

// ---- staging: A f32 tile [32][128] ----
__device__ __forceinline__ void stage_a_f32(const float* __restrict__ g, float* s,
                                            int tid, int kt) {
  int row = tid & 127, c = tid >> 7;  // c in 0..1
  const float* src = g + (size_t)row * HDIM + kt * BK + c * 16;
  float4 v0 = *(const float4*)(src);
  float4 v1 = *(const float4*)(src + 4);
  float4 v2 = *(const float4*)(src + 8);
  float4 v3 = *(const float4*)(src + 12);
  int k0 = c * 16;
  s[(k0 + 0) * BMR + row] = v0.x;  s[(k0 + 1) * BMR + row] = v0.y;
  s[(k0 + 2) * BMR + row] = v0.z;  s[(k0 + 3) * BMR + row] = v0.w;
  s[(k0 + 4) * BMR + row] = v1.x;  s[(k0 + 5) * BMR + row] = v1.y;
  s[(k0 + 6) * BMR + row] = v1.z;  s[(k0 + 7) * BMR + row] = v1.w;
  s[(k0 + 8) * BMR + row] = v2.x;  s[(k0 + 9) * BMR + row] = v2.y;
  s[(k0 + 10) * BMR + row] = v2.z; s[(k0 + 11) * BMR + row] = v2.w;
  s[(k0 + 12) * BMR + row] = v3.x; s[(k0 + 13) * BMR + row] = v3.y;
  s[(k0 + 14) * BMR + row] = v3.z; s[(k0 + 15) * BMR + row] = v3.w;
}

// ---- staging: A bitpacked-spike tile [32][128] (bits -> exact 0.0f/1.0f) ----
__device__ __forceinline__ void stage_a_u1(const unsigned char* __restrict__ g, float* s,
                                           int tid, int kt) {
  int row = tid & 127, c = tid >> 7;  // c in 0..1
  unsigned short v =
      *(const unsigned short*)(g + (size_t)row * SPB + kt * 4 + c * 2);
  int k0 = c * 16;
#pragma unroll
  for (int q = 0; q < 16; ++q)
    s[(k0 + q) * BMR + row] = (float)((v >> q) & 1u);
}

// ---- staging: B (weights) tile [32][64] ----
__device__ __forceinline__ void stage_b(const float* __restrict__ g, float* s,
                                        int tid, int kt) {
  int row = tid & 63, c = tid >> 6;  // c in 0..3
  const float* src = g + (size_t)row * HDIM + kt * BK + c * 8;
  float4 v0 = *(const float4*)(src);
  float4 v1 = *(const float4*)(src + 4);
  int k0 = c * 8;
  s[(k0 + 0) * BNC + row] = v0.x; s[(k0 + 1) * BNC + row] = v0.y;
  s[(k0 + 2) * BNC + row] = v0.z; s[(k0 + 3) * BNC + row] = v0.w;
  s[(k0 + 4) * BNC + row] = v1.x; s[(k0 + 5) * BNC + row] = v1.y;
  s[(k0 + 6) * BNC + row] = v1.z; s[(k0 + 7) * BNC + row] = v1.w;
}

// one K-pass: kc=512-panel ascending FMA chain for a 4x8 micro-tile.
// m0 = (tid>>3)*4, n0 = (tid&7)*8. Single-buffered, 2 barriers per BK=32 tile.
template <bool AU1>
__device__ __forceinline__ void kpass(const void* __restrict__ Ag,
                                      const float* __restrict__ Bg,
                                      float* sA, float* sB, int tid, int m0, int n0,
                                      float csum[4][8]) {
  float p[4][8];
#pragma unroll
  for (int m = 0; m < 4; ++m)
#pragma unroll
    for (int n = 0; n < 8; ++n) { csum[m][n] = 0.0f; p[m][n] = 0.0f; }

#pragma unroll 1
  for (int kt = 0; kt < NKT; ++kt) {
    if (AU1) stage_a_u1((const unsigned char*)Ag, sA, tid, kt);
    else     stage_a_f32((const float*)Ag, sA, tid, kt);
    stage_b(Bg, sB, tid, kt);
    __syncthreads();
#pragma unroll
    for (int k = 0; k < BK; ++k) {
      float a[4], b[8];
      *(float4*)&a[0] = *(const float4*)&sA[k * BMR + m0];
      *(float4*)&b[0] = *(const float4*)&sB[k * BNC + n0];
      *(float4*)&b[4] = *(const float4*)&sB[k * BNC + n0 + 4];
#pragma unroll
      for (int m = 0; m < 4; ++m)
#pragma unroll
        for (int n = 0; n < 8; ++n)
          p[m][n] = __builtin_fmaf(a[m], b[n], p[m][n]);
    }
    if (((kt + 1) * BK) % KC == 0) {  // panel boundary: C += panel
#pragma unroll
      for (int m = 0; m < 4; ++m)
#pragma unroll
        for (int n = 0; n < 8; ++n) { csum[m][n] = csum[m][n] + p[m][n]; p[m][n] = 0.0f; }
    }
    __syncthreads();
  }
}

// cur1 = x@W1.T + b1
__global__ __launch_bounds__(256) void gemm_cur(const float* __restrict__ A,
                                                const float* __restrict__ B,
                                                const float* __restrict__ bias,
                                                float* __restrict__ outv) {
  __shared__ float sA[BK * BMR];
  __shared__ float sB[BK * BNC];
  const int tid = threadIdx.x;
  const int m0 = (tid >> 3) * 4, n0 = (tid & 7) * 8;
  const int bm = blockIdx.y, bn = blockIdx.x;
  float csum[4][8];
  kpass<false>(A + (size_t)bm * BMR * HDIM, B + (size_t)bn * BNC * HDIM,
               sA, sB, tid, m0, n0, csum);
  const int colb = bn * BNC + n0;
  float4 bia0 = *(const float4*)&bias[colb];
  float4 bia1 = *(const float4*)&bias[colb + 4];
  const float bi[8] = {bia0.x, bia0.y, bia0.z, bia0.w, bia1.x, bia1.y, bia1.z, bia1.w};
#pragma unroll
  for (int m = 0; m < 4; ++m) {
    size_t idx = (size_t)(bm * BMR + m0 + m) * HDIM + colb;
    float o[8];
#pragma unroll
    for (int n = 0; n < 8; ++n) o[n] = csum[m][n] + bi[n];
    *(float4*)&outv[idx] = *(float4*)&o[0];
    *(float4*)&outv[idx + 4] = *(float4*)&o[4];
  }
}

// t=0 layer1 (spikes exactly +0): mem1 = ((((0.5*0+cur1)+0)+V1b)-0); spike bits out.
__global__ __launch_bounds__(256) void l1_t0(const float* __restrict__ cur1,
                                             const float* __restrict__ vb,
                                             float* __restrict__ memv,
                                             unsigned char* __restrict__ spk_out) {
  size_t i = ((size_t)blockIdx.x * 256 + threadIdx.x) * 8;
  int col = (int)(i & (HDIM - 1));
  size_t row = i >> 10;
  float au[8], tn[8];
  *(float4*)&au[0] = *(const float4*)&cur1[i];
  *(float4*)&au[4] = *(const float4*)&cur1[i + 4];
  float4 v0 = *(const float4*)&vb[col];
  float4 v1 = *(const float4*)&vb[col + 4];
  const float vbv[8] = {v0.x, v0.y, v0.z, v0.w, v1.x, v1.y, v1.z, v1.w};
  unsigned int bits = 0;
#pragma unroll
  for (int n = 0; n < 8; ++n) {
    float t = 0.5f * 0.0f;
    t = t + au[n];
    t = t + 0.0f;
    t = t + vbv[n];
    t = t - 0.0f;
    tn[n] = t;
    bits |= (((t - 1.0f) > 0.0f) ? 1u : 0u) << n;
  }
  *(float4*)&memv[i] = *(float4*)&tn[0];
  *(float4*)&memv[i + 4] = *(float4*)&tn[4];
  spk_out[row * SPB + (col >> 3)] = (unsigned char)bits;
}

// layer1: rec1 = spk1p@V1w.T ; mem1 = 0.5*mem1 + cur1 + rec1 + V1b - reset
__global__ __launch_bounds__(256) void gemm_l1(
    const unsigned char* __restrict__ A, const float* __restrict__ B,
    const float* __restrict__ vb, const float* __restrict__ cur1,
    float* __restrict__ memv, unsigned char* __restrict__ spk_out) {
  __shared__ float sA[BK * BMR];
  __shared__ float sB[BK * BNC];
  const int tid = threadIdx.x;
  const int m0 = (tid >> 3) * 4, n0 = (tid & 7) * 8;
  const int bm = blockIdx.y, bn = blockIdx.x;
  float csum[4][8];
  kpass<true>(A + (size_t)bm * BMR * SPB, B + (size_t)bn * BNC * HDIM,
              sA, sB, tid, m0, n0, csum);
  const int colb = bn * BNC + n0;
  float4 v0 = *(const float4*)&vb[colb];
  float4 v1 = *(const float4*)&vb[colb + 4];
  const float vbv[8] = {v0.x, v0.y, v0.z, v0.w, v1.x, v1.y, v1.z, v1.w};
#pragma unroll
  for (int m = 0; m < 4; ++m) {
    size_t row = (size_t)(bm * BMR + m0 + m);
    size_t idx = row * HDIM + colb;
    float mo[8], au[8], tn[8];
    *(float4*)&mo[0] = *(const float4*)&memv[idx];
    *(float4*)&mo[4] = *(const float4*)&memv[idx + 4];
    *(float4*)&au[0] = *(const float4*)&cur1[idx];
    *(float4*)&au[4] = *(const float4*)&cur1[idx + 4];
    unsigned int bits = 0;
#pragma unroll
    for (int n = 0; n < 8; ++n) {
      float reset = (mo[n] > 1.0f) ? 1.0f : 0.0f;
      float t = 0.5f * mo[n];
      t = t + au[n];
      t = t + csum[m][n];
      t = t + vbv[n];
      t = t - reset;
      tn[n] = t;
      bits |= (((t - 1.0f) > 0.0f) ? 1u : 0u) << n;
    }
    *(float4*)&memv[idx] = *(float4*)&tn[0];
    *(float4*)&memv[idx + 4] = *(float4*)&tn[4];
    spk_out[row * SPB + (colb >> 3)] = (unsigned char)bits;
  }
}

// layer2 fused: cur2 = spk1n@W2.T + b2 ; rec2 = spk2p@V2w.T (skip2 -> exact +0);
// mem2 = 0.5*mem2 + cur2 + rec2 + V2b - reset ; spike bits/ssum out.
__global__ __launch_bounds__(256) void gemm_l2f(
    const unsigned char* __restrict__ A1, const float* __restrict__ B1,
    const unsigned char* __restrict__ A2, const float* __restrict__ B2,
    const float* __restrict__ bias, const float* __restrict__ vb,
    float* __restrict__ memv, unsigned char* __restrict__ spk_out,
    unsigned char* __restrict__ ssum, int skip2) {
  __shared__ float sA[BK * BMR];
  __shared__ float sB[BK * BNC];
  const int tid = threadIdx.x;
  const int m0 = (tid >> 3) * 4, n0 = (tid & 7) * 8;
  const int bm = blockIdx.y, bn = blockIdx.x;
  float dot1[4][8], csum[4][8];
  kpass<true>(A1 + (size_t)bm * BMR * SPB, B1 + (size_t)bn * BNC * HDIM,
              sA, sB, tid, m0, n0, dot1);
  if (skip2) {
#pragma unroll
    for (int m = 0; m < 4; ++m)
#pragma unroll
      for (int n = 0; n < 8; ++n) csum[m][n] = 0.0f;  // zero-spike chain == +0
  } else {
    __syncthreads();
    kpass<true>(A2 + (size_t)bm * BMR * SPB, B2 + (size_t)bn * BNC * HDIM,
                sA, sB, tid, m0, n0, csum);
  }
  const int colb = bn * BNC + n0;
  float4 b0 = *(const float4*)&bias[colb];
  float4 b1v = *(const float4*)&bias[colb + 4];
  const float bi[8] = {b0.x, b0.y, b0.z, b0.w, b1v.x, b1v.y, b1v.z, b1v.w};
  float4 v0 = *(const float4*)&vb[colb];
  float4 v1 = *(const float4*)&vb[colb + 4];
  const float vbv[8] = {v0.x, v0.y, v0.z, v0.w, v1.x, v1.y, v1.z, v1.w};
#pragma unroll
  for (int m = 0; m < 4; ++m) {
    size_t row = (size_t)(bm * BMR + m0 + m);
    size_t idx = row * HDIM + colb;
    float mo[8], tn[8];
    *(float4*)&mo[0] = *(const float4*)&memv[idx];
    *(float4*)&mo[4] = *(const float4*)&memv[idx + 4];
    unsigned int bits = 0;
#pragma unroll
    for (int n = 0; n < 8; ++n) {
      float reset = (mo[n] > 1.0f) ? 1.0f : 0.0f;
      float cur2 = dot1[m][n] + bi[n];
      float t = 0.5f * mo[n];
      t = t + cur2;
      t = t + csum[m][n];
      t = t + vbv[n];
      t = t - reset;
      tn[n] = t;
      bits |= (((t - 1.0f) > 0.0f) ? 1u : 0u) << n;
    }
    *(float4*)&memv[idx] = *(float4*)&tn[0];
    *(float4*)&memv[idx + 4] = *(float4*)&tn[4];
    spk_out[row * SPB + (colb >> 3)] = (unsigned char)bits;
    unsigned long long old = *(unsigned long long*)&ssum[idx];
    unsigned long long ns = 0;
#pragma unroll
    for (int n = 0; n < 8; ++n) {
      unsigned char c = (unsigned char)(((old >> (8 * n)) & 0xFF) + ((bits >> n) & 1u));
      ns |= ((unsigned long long)c) << (8 * n);
    }
    *(unsigned long long*)&ssum[idx] = ns;
  }
}

// out[b,o] = ((ssum[b,:]/25) . W3[o,:]) + b3[o], kc=512 panel rounding.
__global__ __launch_bounds__(256) void out_blas(const unsigned char* __restrict__ ssum,
                                                const float* __restrict__ W3,
                                                const float* __restrict__ b3,
                                                float* __restrict__ out) {
  int t = blockIdx.x * 256 + threadIdx.x;
  int b = t >> 4, o = t & 15;
  if (o >= 10) return;
  const unsigned char* sp = ssum + (size_t)b * HDIM;
  const float* wp = W3 + (size_t)o * HDIM;
  float csum = 0.0f, p = 0.0f;
#pragma unroll 4
  for (int k = 0; k < HDIM; ++k) {
    float sv = (float)sp[k] / 25.0f;
    p = __builtin_fmaf(sv, wp[k], p);
    if ((k + 1) % KC == 0) { csum = csum + p; p = 0.0f; }
  }
  out[(size_t)b * 10 + o] = csum + b3[o];
}

extern "C" void kernel_launch(void* const* d_in, const int* in_sizes, int n_in,
                              void* d_out, int out_size, void* d_ws, size_t ws_size,
                              hipStream_t stream) {
  const float* x = (const float*)d_in[0];
  const float* W1 = (const float*)d_in[1];
  const float* b1 = (const float*)d_in[2];
  const float* V1w = (const float*)d_in[3];
  const float* V1b = (const float*)d_in[4];
  const float* W2 = (const float*)d_in[5];
  const float* b2 = (const float*)d_in[6];
  const float* V2w = (const float*)d_in[7];
  const float* V2b = (const float*)d_in[8];
  const float* W3 = (const float*)d_in[9];
  const float* b3 = (const float*)d_in[10];
  float* out = (float*)d_out;

  char* ws = (char*)d_ws;
  // per-row: cur1, mem1, mem2 (f32) + 4 bitpacked spike bufs + ssum (u8)
  const size_t per_row = (size_t)HDIM * 4 * 3 + 4 * SPB + (size_t)HDIM;
  size_t rows = BATCH;
  while (rows > 128 && rows * per_row > ws_size) rows >>= 1;
  const int nchunk = (int)(BATCH / rows);
  const size_t RH = rows * (size_t)HDIM;
  const size_t RS = rows * (size_t)SPB;

  size_t off = 0;
  float* cur1 = (float*)(ws + off); off += RH * 4;
  float* mem1 = (float*)(ws + off); off += RH * 4;
  float* mem2 = (float*)(ws + off); off += RH * 4;
  unsigned char *spk1[2], *spk2[2];
  spk1[0] = (unsigned char*)(ws + off); off += RS;
  spk1[1] = (unsigned char*)(ws + off); off += RS;
  spk2[0] = (unsigned char*)(ws + off); off += RS;
  spk2[1] = (unsigned char*)(ws + off); off += RS;
  unsigned char* ssum = (unsigned char*)(ws + off); off += RH;

  dim3 grid(HDIM / BNC, (unsigned)(rows / BMR));  // (16, rows/128)

  for (int c = 0; c < nchunk; ++c) {
    const float* xc = x + (size_t)c * RH;
    float* outc = out + (size_t)c * rows * 10;

    hipMemsetAsync(mem2, 0, RH * 4, stream);
    hipMemsetAsync(ssum, 0, RH, stream);

    // cur1 = x@W1.T + b1 (loop-invariant)
    gemm_cur<<<grid, 256, 0, stream>>>(xc, W1, b1, cur1);

    for (int t = 0; t < NSTEP; ++t) {
      int rd = t & 1, wr = rd ^ 1;
      if (t == 0) {
        l1_t0<<<(unsigned)(RH / (256 * 8)), 256, 0, stream>>>(cur1, V1b, mem1, spk1[wr]);
      } else {
        gemm_l1<<<grid, 256, 0, stream>>>(spk1[rd], V1w, V1b, cur1, mem1, spk1[wr]);
      }
      gemm_l2f<<<grid, 256, 0, stream>>>(spk1[wr], W2, spk2[rd], V2w, b2, V2b,
                                         mem2, spk2[wr], ssum, t == 0 ? 1 : 0);
    }
    out_blas<<<(unsigned)(rows * 16 / 256), 256, 0, stream>>>(ssum, W3, b3, outc);
  }
}